// Round 8
// baseline (377.146 us; speedup 1.0000x reference)
//
#include <hip/hip_runtime.h>

// Problem constants
#define BB 4
#define SS 4096
#define DIN 1024      // K for both GEMMs
#define DH 1024       // combined fast+slow channels
#define PN 2048       // GEMM1 logical output cols (z -> Zarr, h~ -> Harr)
#define MM (BB*SS)    // 16384 rows
#define NC 64         // scan chunks
#define CL 64         // chunk length (NC*CL == SS)

typedef unsigned short ushort_t;
typedef __attribute__((ext_vector_type(8))) short bf16x8;
typedef __attribute__((ext_vector_type(8))) unsigned short u16x8;
typedef __attribute__((ext_vector_type(4))) float f32x4;
typedef __attribute__((ext_vector_type(4))) unsigned short u16x4;

__device__ inline float bf2f(ushort_t u) {
    union { float f; unsigned int i; } v; v.i = ((unsigned int)u) << 16; return v.f;
}
__device__ inline ushort_t f2bf(float f) {
    union { float f; unsigned int i; } v; v.f = f;
    unsigned int r = v.i + 0x7fffu + ((v.i >> 16) & 1u);  // round-to-nearest-even
    return (ushort_t)(r >> 16);
}
__device__ inline float sigmoidf_(float x) { return 1.0f / (1.0f + __expf(-x)); }

__device__ inline void load_lds16(const void* g, void* l) {
    __builtin_amdgcn_global_load_lds(
        (const __attribute__((address_space(1))) void*)g,
        (__attribute__((address_space(3))) void*)l, 16, 0, 0);
}

// ---------------------------------------------------------------------------
// Fallback (ws too small telemetry): write fp32 zeros to out.
__global__ void zero_out_kernel(float* out, int n) {
    int i = blockIdx.x * 256 + threadIdx.x;
    if (i < n) out[i] = 0.0f;
}

// ---------------------------------------------------------------------------
// Fused prep kernel, region-switched on blockIdx.x:
//  [0,512):        transpose 4x (1024x512 fp32 -> bf16 NxK) into WcatT
//  [512,768):      transpose Wg (1024x1024) into WgT
//  [768,17152):    cvt x fp32 -> bf16 (Xb)
//  [17152,17160):  bias concat (fp32)
#define PREP_NBLK 17160
__global__ __launch_bounds__(256) void prep_kernel(
    const float* __restrict__ x,
    const float* __restrict__ Wzf, const float* __restrict__ Wzs,
    const float* __restrict__ Whf, const float* __restrict__ Whs,
    const float* __restrict__ Wg,
    const float* __restrict__ bzf, const float* __restrict__ bzs,
    const float* __restrict__ bhf, const float* __restrict__ bhs,
    ushort_t* __restrict__ WcatT, ushort_t* __restrict__ WgT,
    ushort_t* __restrict__ Xb, float* __restrict__ bcat)
{
    __shared__ ushort_t tile[64][65];
    const int bx = blockIdx.x, tid = threadIdx.x;

    if (bx < 768) {
        const float* src; ushort_t* dst; int srcN, t;
        if (bx < 512) {
            int wi = bx >> 7; t = bx & 127; srcN = 512;
            const float* S[4] = {Wzf, Wzs, Whf, Whs};
            src = S[wi];
            dst = WcatT + (size_t)(wi * 512) * DIN;
        } else {
            t = bx - 512; srcN = 1024; src = Wg; dst = WgT;
        }
        const int k0 = (t & 15) * 64, n0 = (t >> 4) * 64;
        const int tx = tid & 63, ty = tid >> 6;
        #pragma unroll
        for (int i = ty; i < 64; i += 4)
            tile[i][tx] = f2bf(src[(size_t)(k0 + i) * srcN + n0 + tx]);
        __syncthreads();
        #pragma unroll
        for (int i = ty; i < 64; i += 4)
            dst[(size_t)(n0 + i) * DIN + k0 + tx] = tile[tx][i];
    } else if (bx < 17152) {
        size_t i = ((size_t)(bx - 768) * 256 + tid) * 4;
        float4 v = *(const float4*)(x + i);
        u16x4 o;
        o.x = f2bf(v.x); o.y = f2bf(v.y); o.z = f2bf(v.z); o.w = f2bf(v.w);
        *(u16x4*)(Xb + i) = o;
    } else {
        int i = (bx - 17152) * 256 + tid;  // 0..2047
        float v = (i < 512) ? bzf[i] : (i < 1024) ? bzs[i - 512]
                : (i < 1536) ? bhf[i - 1024] : bhs[i - 1536];
        bcat[i] = v;
    }
}

// ---------------------------------------------------------------------------
// GEMM1: [Z|H~](16384 x 2048) = Xb(16384x1024) * WcatT(2048x1024)^T
// 128x128 tile, BK=64, 4 waves 2x2. XCD-swizzled 1-D grid, XOR-swizzled LDS
// (0 bank conflicts, r5). Epilogue: LDS repack -> 16B coalesced bf16 stores.
#define NB1 (PN/128)
__global__ __launch_bounds__(256) void gemm1_mfma(
    const ushort_t* __restrict__ A, const ushort_t* __restrict__ Bt,
    const float* __restrict__ bias,
    ushort_t* __restrict__ Zarr, ushort_t* __restrict__ Harr)
{
    __shared__ alignas(16) unsigned char smem[34816];
    ushort_t* As  = (ushort_t*)smem;            // 128x64 u16
    ushort_t* Bs  = (ushort_t*)(smem + 16384);  // 128x64 u16
    ushort_t* R16 = (ushort_t*)smem;            // repack: 128 rows, stride 136

    const int tid  = threadIdx.x;
    const int lane = tid & 63;
    const int wave = tid >> 6;
    const int wm   = wave & 1;
    const int wn   = wave >> 1;
    const int lrow = lane & 15;
    const int kgrp = lane >> 4;

    const int id  = blockIdx.x;
    const int xcd = id & 7;
    const int s   = id >> 3;
    const int mBase = (xcd + 8 * (s / NB1)) * 128;
    const int nBase = (s % NB1) * 128;

    f32x4 acc[4][4] = {};
    const ushort_t* Ablk = A  + (size_t)mBase * DIN;
    const ushort_t* Bblk = Bt + (size_t)nBase * DIN;

    for (int k0 = 0; k0 < DIN; k0 += 64) {
        #pragma unroll
        for (int i = 0; i < 4; i++) {
            int idx = i * 256 + tid;
            int r   = idx >> 3;
            int cc  = ((idx & 7) ^ (r & 7)) * 8;
            load_lds16(Ablk + (size_t)r * DIN + k0 + cc, &As[idx * 8]);
            load_lds16(Bblk + (size_t)r * DIN + k0 + cc, &Bs[idx * 8]);
        }
        __syncthreads();
        #pragma unroll
        for (int kk = 0; kk < 64; kk += 32) {
            const int c0 = (kk >> 3) + kgrp;
            bf16x8 af[4], bfr[4];
            #pragma unroll
            for (int mt = 0; mt < 4; mt++) {
                int r = wm * 64 + mt * 16 + lrow;
                af[mt] = *(const bf16x8*)&As[r * 64 + (c0 ^ (r & 7)) * 8];
            }
            #pragma unroll
            for (int nt = 0; nt < 4; nt++) {
                int r = wn * 64 + nt * 16 + lrow;
                bfr[nt] = *(const bf16x8*)&Bs[r * 64 + (c0 ^ (r & 7)) * 8];
            }
            #pragma unroll
            for (int mt = 0; mt < 4; mt++)
                #pragma unroll
                for (int nt = 0; nt < 4; nt++)
                    acc[mt][nt] = __builtin_amdgcn_mfma_f32_16x16x32_bf16(
                        af[mt], bfr[nt], acc[mt][nt], 0, 0, 0);
        }
        __syncthreads();
    }

    // Epilogue: C/D layout col=lane&15, row=(lane>>4)*4+reg [m89/m91].
    const bool isz = (nBase < DH);
    ushort_t* Dst  = isz ? Zarr : Harr;
    const int dcb  = nBase - (isz ? 0 : DH);
    const int rquad = (lane >> 4) * 4;

    #pragma unroll
    for (int nt = 0; nt < 4; nt++) {
        int colrel = wn * 64 + nt * 16 + lrow;
        float bv = bias[nBase + colrel];
        #pragma unroll
        for (int mt = 0; mt < 4; mt++) {
            int rowrel = wm * 64 + mt * 16 + rquad;
            #pragma unroll
            for (int r = 0; r < 4; r++) {
                float v = acc[mt][nt][r] + bv;
                if (isz) v = sigmoidf_(v);
                R16[(rowrel + r) * 136 + colrel] = f2bf(v);
            }
        }
    }
    __syncthreads();
    #pragma unroll
    for (int it = 0; it < 8; it++) {
        int cid = it * 256 + tid;           // 0..2047
        int rr  = cid >> 4, cc = (cid & 15) * 8;
        u16x8 v = *(const u16x8*)&R16[rr * 136 + cc];
        *(u16x8*)&Dst[(size_t)(mBase + rr) * DH + dcb + cc] = v;
    }
}

// ---------------------------------------------------------------------------
// GEMM2: out = sigmoid(H @ WgT^T + bg) * H  (fp32 out).
// h values for the epilogue are CAPTURED from the A-staging LDS at the
// iteration k0 == nBase + wn*64 (As then holds h[rows][out-cols]) -- no
// global Hbf re-read. Epilogue repacks g*h through LDS -> float4 stores.
#define NB2 (DH/128)
__global__ __launch_bounds__(256) void gemm2_mfma(
    const ushort_t* __restrict__ A, const ushort_t* __restrict__ Bt,
    const float* __restrict__ bg, float* __restrict__ Out)
{
    __shared__ alignas(16) unsigned char smem[34816];
    ushort_t* As  = (ushort_t*)smem;
    ushort_t* Bs  = (ushort_t*)(smem + 16384);
    float*    R32 = (float*)smem;               // repack: 64 rows, stride 132

    const int tid  = threadIdx.x;
    const int lane = tid & 63;
    const int wave = tid >> 6;
    const int wm   = wave & 1;
    const int wn   = wave >> 1;
    const int lrow = lane & 15;
    const int kgrp = lane >> 4;
    const int rquad = (lane >> 4) * 4;

    const int id  = blockIdx.x;
    const int xcd = id & 7;
    const int s   = id >> 3;
    const int mBase = (xcd + 8 * (s / NB2)) * 128;
    const int nBase = (s % NB2) * 128;

    f32x4 acc[4][4] = {};
    ushort_t hcap[4][4][4];
    const int kcap = nBase + wn * 64;           // wave-uniform capture iteration

    const ushort_t* Ablk = A  + (size_t)mBase * DH;
    const ushort_t* Bblk = Bt + (size_t)nBase * DIN;

    for (int k0 = 0; k0 < DIN; k0 += 64) {
        #pragma unroll
        for (int i = 0; i < 4; i++) {
            int idx = i * 256 + tid;
            int r   = idx >> 3;
            int cc  = ((idx & 7) ^ (r & 7)) * 8;
            load_lds16(Ablk + (size_t)r * DH  + k0 + cc, &As[idx * 8]);
            load_lds16(Bblk + (size_t)r * DIN + k0 + cc, &Bs[idx * 8]);
        }
        __syncthreads();

        if (k0 == kcap) {   // capture h fragment for epilogue (wave-uniform)
            #pragma unroll
            for (int mt = 0; mt < 4; mt++)
                #pragma unroll
                for (int r = 0; r < 4; r++) {
                    int rrr = wm * 64 + mt * 16 + rquad + r;
                    int sw  = rrr & 7;
                    #pragma unroll
                    for (int nt = 0; nt < 4; nt++) {
                        int ck = nt * 16 + lrow;
                        hcap[mt][nt][r] = As[rrr * 64 + (((ck >> 3) ^ sw) * 8) + (ck & 7)];
                    }
                }
        }

        #pragma unroll
        for (int kk = 0; kk < 64; kk += 32) {
            const int c0 = (kk >> 3) + kgrp;
            bf16x8 af[4], bfr[4];
            #pragma unroll
            for (int mt = 0; mt < 4; mt++) {
                int r = wm * 64 + mt * 16 + lrow;
                af[mt] = *(const bf16x8*)&As[r * 64 + (c0 ^ (r & 7)) * 8];
            }
            #pragma unroll
            for (int nt = 0; nt < 4; nt++) {
                int r = wn * 64 + nt * 16 + lrow;
                bfr[nt] = *(const bf16x8*)&Bs[r * 64 + (c0 ^ (r & 7)) * 8];
            }
            #pragma unroll
            for (int mt = 0; mt < 4; mt++)
                #pragma unroll
                for (int nt = 0; nt < 4; nt++)
                    acc[mt][nt] = __builtin_amdgcn_mfma_f32_16x16x32_bf16(
                        af[mt], bfr[nt], acc[mt][nt], 0, 0, 0);
        }
        __syncthreads();
    }

    // Epilogue: two 64-row halves through LDS (fp32, stride 132).
    #pragma unroll
    for (int h = 0; h < 2; h++) {
        if (wm == h) {
            #pragma unroll
            for (int nt = 0; nt < 4; nt++) {
                int colrel = wn * 64 + nt * 16 + lrow;
                float bv = bg[nBase + colrel];
                #pragma unroll
                for (int mt = 0; mt < 4; mt++) {
                    int rloc = mt * 16 + rquad;
                    #pragma unroll
                    for (int r = 0; r < 4; r++) {
                        float g  = sigmoidf_(acc[mt][nt][r] + bv);
                        float hv = bf2f(hcap[mt][nt][r]);
                        R32[(rloc + r) * 132 + colrel] = g * hv;
                    }
                }
            }
        }
        __syncthreads();
        #pragma unroll
        for (int it = 0; it < 8; it++) {
            int cid = it * 256 + tid;            // 0..2047
            int rr  = cid >> 5, cc4 = (cid & 31) * 4;
            float4 v = *(const float4*)&R32[rr * 132 + cc4];
            *(float4*)&Out[(size_t)(mBase + h * 64 + rr) * DH + nBase + cc4] = v;
        }
        __syncthreads();
    }
}

// ---------------------------------------------------------------------------
// Scan pass 1: per-chunk aggregates, 4 channels/thread (u16x4 = 8B loads).
__global__ __launch_bounds__(256) void scan_chunk_agg(
    const ushort_t* __restrict__ Zarr, const ushort_t* __restrict__ Harr,
    float* __restrict__ Agg, float* __restrict__ Bagg)
{
    const int c4    = threadIdx.x * 4;
    const int chunk = blockIdx.x;
    const int b     = blockIdx.y;
    const size_t s0 = ((size_t)b * SS + (size_t)chunk * CL) * DH + c4;
    const ushort_t* Zp = Zarr + s0;
    const ushort_t* Hp = Harr + s0;

    float A0 = 1.0f, A1 = 1.0f, A2 = 1.0f, A3 = 1.0f;
    float B0 = 0.0f, B1 = 0.0f, B2 = 0.0f, B3 = 0.0f;
    #pragma unroll 8
    for (int t = 0; t < CL; t++) {
        u16x4 zv = *(const u16x4*)(Zp + (size_t)t * DH);
        u16x4 hv = *(const u16x4*)(Hp + (size_t)t * DH);
        float z0 = bf2f(zv.x), z1 = bf2f(zv.y), z2 = bf2f(zv.z), z3 = bf2f(zv.w);
        float h0 = bf2f(hv.x), h1 = bf2f(hv.y), h2 = bf2f(hv.z), h3 = bf2f(hv.w);
        A0 *= 1.0f - z0;  B0 = (1.0f - z0) * B0 + z0 * h0;
        A1 *= 1.0f - z1;  B1 = (1.0f - z1) * B1 + z1 * h1;
        A2 *= 1.0f - z2;  B2 = (1.0f - z2) * B2 + z2 * h2;
        A3 *= 1.0f - z3;  B3 = (1.0f - z3) * B3 + z3 * h3;
    }
    const size_t idx = ((size_t)(b * NC + chunk)) * DH + c4;
    *(float4*)(Agg  + idx) = make_float4(A0, A1, A2, A3);
    *(float4*)(Bagg + idx) = make_float4(B0, B1, B2, B3);
}

// Scan pass 2: carry across chunks. 4096 threads, 64 sequential L2-hot steps.
__global__ void scan_carry(const float* __restrict__ Agg, const float* __restrict__ Bagg,
                           float* __restrict__ Hinit)
{
    const int i = blockIdx.x * 256 + threadIdx.x;
    const int b = i >> 10, c = i & 1023;
    float h = 0.0f;
    for (int j = 0; j < NC; j++) {
        const size_t idx = ((size_t)(b * NC + j)) * DH + c;
        Hinit[idx] = h;
        h = Agg[idx] * h + Bagg[idx];
    }
}

// Scan pass 3: re-apply with chunk-initial h; h (bf16) in place over Harr.
__global__ __launch_bounds__(256) void scan_apply(
    const ushort_t* __restrict__ Zarr, ushort_t* Harr, const float* __restrict__ Hinit)
{
    const int c4    = threadIdx.x * 4;
    const int chunk = blockIdx.x;
    const int b     = blockIdx.y;
    const size_t s0 = ((size_t)b * SS + (size_t)chunk * CL) * DH + c4;
    const ushort_t* Zp = Zarr + s0;
    ushort_t*       Hp = Harr + s0;

    float4 hi = *(const float4*)(Hinit + ((size_t)(b * NC + chunk)) * DH + c4);
    float h0 = hi.x, h1 = hi.y, h2 = hi.z, h3 = hi.w;
    #pragma unroll 8
    for (int t = 0; t < CL; t++) {
        u16x4 zv = *(const u16x4*)(Zp + (size_t)t * DH);
        u16x4 hv = *(const u16x4*)(Hp + (size_t)t * DH);
        float z0 = bf2f(zv.x), z1 = bf2f(zv.y), z2 = bf2f(zv.z), z3 = bf2f(zv.w);
        float t0 = bf2f(hv.x), t1 = bf2f(hv.y), t2 = bf2f(hv.z), t3 = bf2f(hv.w);
        h0 = (1.0f - z0) * h0 + z0 * t0;
        h1 = (1.0f - z1) * h1 + z1 * t1;
        h2 = (1.0f - z2) * h2 + z2 * t2;
        h3 = (1.0f - z3) * h3 + z3 * t3;
        u16x4 o;
        o.x = f2bf(h0); o.y = f2bf(h1); o.z = f2bf(h2); o.w = f2bf(h3);
        *(u16x4*)(Hp + (size_t)t * DH) = o;
    }
}

// ---------------------------------------------------------------------------
extern "C" void kernel_launch(void* const* d_in, const int* in_sizes, int n_in,
                              void* d_out, int out_size, void* d_ws, size_t ws_size,
                              hipStream_t stream)
{
    const float* x   = (const float*)d_in[0];
    const float* Wzf = (const float*)d_in[1];
    const float* bzf = (const float*)d_in[2];
    const float* Whf = (const float*)d_in[3];
    const float* bhf = (const float*)d_in[4];
    const float* Wzs = (const float*)d_in[5];
    const float* bzs = (const float*)d_in[6];
    const float* Whs = (const float*)d_in[7];
    const float* bhs = (const float*)d_in[8];
    const float* Wg  = (const float*)d_in[9];
    const float* bg  = (const float*)d_in[10];

    const size_t NEED = (size_t)42 << 20;
    if (ws_size < NEED) {
        zero_out_kernel<<<(MM * DH + 255) / 256, 256, 0, stream>>>((float*)d_out, MM * DH);
        return;
    }

    char* ws = (char*)d_ws;
    ushort_t* WcatT = (ushort_t*)(ws);                                    // 0..4 MiB
    ushort_t* WgT   = (ushort_t*)(ws + ((size_t)4 << 20));                // 4..6 MiB
    float*    bcat  = (float*)   (ws + ((size_t)6 << 20));                // 8 KiB
    float*    Agg   = (float*)   (ws + ((size_t)6 << 20) + (64 << 10));   // 1 MiB
    float*    Bagg  = (float*)   (ws + ((size_t)7 << 20) + (64 << 10));   // 1 MiB
    float*    Hinit = (float*)   (ws + ((size_t)8 << 20) + (64 << 10));   // 1 MiB
    ushort_t* Harr  = (ushort_t*)(ws + ((size_t)10 << 20));               // 10..42 MiB

    ushort_t* Xb   = (ushort_t*)d_out;              // [0..32 MiB): x in bf16
    ushort_t* Zarr = Xb + (size_t)MM * DH;          // [32..64 MiB): post-sigmoid z

    dim3 blk(256);

    prep_kernel<<<PREP_NBLK, blk, 0, stream>>>(
        x, Wzf, Wzs, Whf, Whs, Wg, bzf, bzs, bhf, bhs, WcatT, WgT, Xb, bcat);

    gemm1_mfma<<<(MM / 128) * NB1, blk, 0, stream>>>(Xb, WcatT, bcat, Zarr, Harr);

    scan_chunk_agg<<<dim3(NC, BB), blk, 0, stream>>>(Zarr, Harr, Agg, Bagg);
    scan_carry<<<16, 256, 0, stream>>>(Agg, Bagg, Hinit);
    scan_apply<<<dim3(NC, BB), blk, 0, stream>>>(Zarr, Harr, Hinit);

    gemm2_mfma<<<(MM / 128) * NB2, blk, 0, stream>>>(Harr, WgT, bg, (float*)d_out);
}

// Round 9
// 340.619 us; speedup vs baseline: 1.1072x; 1.1072x over previous
//
#include <hip/hip_runtime.h>

// Problem constants
#define BB 4
#define SS 4096
#define DIN 1024      // K for both GEMMs
#define DH 1024       // combined fast+slow channels
#define PN 2048       // GEMM1 logical output cols (z -> Zarr, h~ -> Harr)
#define MM (BB*SS)    // 16384 rows
#define NC 64         // scan chunks
#define CL 64         // chunk length (NC*CL == SS)

typedef unsigned short ushort_t;
typedef __attribute__((ext_vector_type(8))) short bf16x8;
typedef __attribute__((ext_vector_type(8))) unsigned short u16x8;
typedef __attribute__((ext_vector_type(4))) float f32x4;
typedef __attribute__((ext_vector_type(4))) unsigned short u16x4;

__device__ inline float bf2f(ushort_t u) {
    union { float f; unsigned int i; } v; v.i = ((unsigned int)u) << 16; return v.f;
}
__device__ inline ushort_t f2bf(float f) {
    union { float f; unsigned int i; } v; v.f = f;
    unsigned int r = v.i + 0x7fffu + ((v.i >> 16) & 1u);  // round-to-nearest-even
    return (ushort_t)(r >> 16);
}
__device__ inline float sigmoidf_(float x) { return 1.0f / (1.0f + __expf(-x)); }

__device__ inline void load_lds16(const void* g, void* l) {
    __builtin_amdgcn_global_load_lds(
        (const __attribute__((address_space(1))) void*)g,
        (__attribute__((address_space(3))) void*)l, 16, 0, 0);
}

// ---------------------------------------------------------------------------
// Fallback (ws too small telemetry): write fp32 zeros to out.
__global__ void zero_out_kernel(float* out, int n) {
    int i = blockIdx.x * 256 + threadIdx.x;
    if (i < n) out[i] = 0.0f;
}

// ---------------------------------------------------------------------------
// Fused prep kernel, region-switched on blockIdx.x:
//  [0,512):        transpose 4x (1024x512 fp32 -> bf16 NxK) into WcatT
//  [512,768):      transpose Wg (1024x1024) into WgT
//  [768,17152):    cvt x fp32 -> bf16 (Xb)
//  [17152,17160):  bias concat (fp32)
#define PREP_NBLK 17160
__global__ __launch_bounds__(256) void prep_kernel(
    const float* __restrict__ x,
    const float* __restrict__ Wzf, const float* __restrict__ Wzs,
    const float* __restrict__ Whf, const float* __restrict__ Whs,
    const float* __restrict__ Wg,
    const float* __restrict__ bzf, const float* __restrict__ bzs,
    const float* __restrict__ bhf, const float* __restrict__ bhs,
    ushort_t* __restrict__ WcatT, ushort_t* __restrict__ WgT,
    ushort_t* __restrict__ Xb, float* __restrict__ bcat)
{
    __shared__ ushort_t tile[64][65];
    const int bx = blockIdx.x, tid = threadIdx.x;

    if (bx < 768) {
        const float* src; ushort_t* dst; int srcN, t;
        if (bx < 512) {
            int wi = bx >> 7; t = bx & 127; srcN = 512;
            const float* S[4] = {Wzf, Wzs, Whf, Whs};
            src = S[wi];
            dst = WcatT + (size_t)(wi * 512) * DIN;
        } else {
            t = bx - 512; srcN = 1024; src = Wg; dst = WgT;
        }
        const int k0 = (t & 15) * 64, n0 = (t >> 4) * 64;
        const int tx = tid & 63, ty = tid >> 6;
        #pragma unroll
        for (int i = ty; i < 64; i += 4)
            tile[i][tx] = f2bf(src[(size_t)(k0 + i) * srcN + n0 + tx]);
        __syncthreads();
        #pragma unroll
        for (int i = ty; i < 64; i += 4)
            dst[(size_t)(n0 + i) * DIN + k0 + tx] = tile[tx][i];
    } else if (bx < 17152) {
        size_t i = ((size_t)(bx - 768) * 256 + tid) * 4;
        float4 v = *(const float4*)(x + i);
        u16x4 o;
        o.x = f2bf(v.x); o.y = f2bf(v.y); o.z = f2bf(v.z); o.w = f2bf(v.w);
        *(u16x4*)(Xb + i) = o;
    } else {
        int i = (bx - 17152) * 256 + tid;  // 0..2047
        float v = (i < 512) ? bzf[i] : (i < 1024) ? bzs[i - 512]
                : (i < 1536) ? bhf[i - 1024] : bhs[i - 1536];
        bcat[i] = v;
    }
}

// ---------------------------------------------------------------------------
// GEMM1 (r7-exact): [Z|H~] = Xb * WcatT^T. 128x128 tile, BK=64, 4 waves 2x2.
// XCD-swizzled 1-D grid, XOR-swizzled LDS (0 bank conflicts). Direct stores.
#define NB1 (PN/128)
__global__ __launch_bounds__(256) void gemm1_mfma(
    const ushort_t* __restrict__ A, const ushort_t* __restrict__ Bt,
    const float* __restrict__ bias,
    ushort_t* __restrict__ Zarr, ushort_t* __restrict__ Harr)
{
    __shared__ alignas(16) ushort_t As[128 * 64];
    __shared__ alignas(16) ushort_t Bs[128 * 64];

    const int tid  = threadIdx.x;
    const int lane = tid & 63;
    const int wave = tid >> 6;
    const int wm   = wave & 1;
    const int wn   = wave >> 1;
    const int lrow = lane & 15;
    const int kgrp = lane >> 4;

    const int id  = blockIdx.x;
    const int xcd = id & 7;
    const int s   = id >> 3;
    const int mBase = (xcd + 8 * (s / NB1)) * 128;
    const int nBase = (s % NB1) * 128;

    f32x4 acc[4][4] = {};
    const ushort_t* Ablk = A  + (size_t)mBase * DIN;
    const ushort_t* Bblk = Bt + (size_t)nBase * DIN;

    for (int k0 = 0; k0 < DIN; k0 += 64) {
        #pragma unroll
        for (int i = 0; i < 4; i++) {
            int idx = i * 256 + tid;
            int r   = idx >> 3;
            int cc  = ((idx & 7) ^ (r & 7)) * 8;
            load_lds16(Ablk + (size_t)r * DIN + k0 + cc, &As[idx * 8]);
            load_lds16(Bblk + (size_t)r * DIN + k0 + cc, &Bs[idx * 8]);
        }
        __syncthreads();
        #pragma unroll
        for (int kk = 0; kk < 64; kk += 32) {
            const int c0 = (kk >> 3) + kgrp;
            bf16x8 af[4], bfr[4];
            #pragma unroll
            for (int mt = 0; mt < 4; mt++) {
                int r = wm * 64 + mt * 16 + lrow;
                af[mt] = *(const bf16x8*)&As[r * 64 + (c0 ^ (r & 7)) * 8];
            }
            #pragma unroll
            for (int nt = 0; nt < 4; nt++) {
                int r = wn * 64 + nt * 16 + lrow;
                bfr[nt] = *(const bf16x8*)&Bs[r * 64 + (c0 ^ (r & 7)) * 8];
            }
            #pragma unroll
            for (int mt = 0; mt < 4; mt++)
                #pragma unroll
                for (int nt = 0; nt < 4; nt++)
                    acc[mt][nt] = __builtin_amdgcn_mfma_f32_16x16x32_bf16(
                        af[mt], bfr[nt], acc[mt][nt], 0, 0, 0);
        }
        __syncthreads();
    }

    // Epilogue: C/D layout col=lane&15, row=(lane>>4)*4+reg [m89/m91]. Direct.
    const bool isz = (nBase < DH);
    ushort_t* Dst  = isz ? Zarr : Harr;
    const int csub = isz ? 0 : DH;
    const int row0  = mBase + wm * 64;
    const int col0  = nBase + wn * 64;
    const int rquad = (lane >> 4) * 4;

    #pragma unroll
    for (int nt = 0; nt < 4; nt++) {
        int col  = col0 + nt * 16 + lrow;
        float bv = bias[col];
        int dcol = col - csub;
        #pragma unroll
        for (int mt = 0; mt < 4; mt++) {
            int row = row0 + mt * 16 + rquad;
            ushort_t* p = Dst + (size_t)row * DH + dcol;
            #pragma unroll
            for (int r = 0; r < 4; r++) {
                float v = acc[mt][nt][r] + bv;
                if (isz) v = sigmoidf_(v);
                p[(size_t)r * DH] = f2bf(v);
            }
        }
    }
}

// ---------------------------------------------------------------------------
// GEMM2: out = sigmoid(H @ WgT^T + bg) * H  (fp32 out).
// Epilogue: AFTER the K-loop, stage the 128x128 H-tile into the dead As/Bs
// LDS (exactly 32 KiB, XOR chunk swizzle -> <=2-way = free) with coalesced
// 16B global loads, then per-element ds reads. No VGPR growth, LDS stays 32K.
#define NB2 (DH/128)
__global__ __launch_bounds__(256) void gemm2_mfma(
    const ushort_t* __restrict__ A, const ushort_t* __restrict__ Bt,
    const float* __restrict__ bg, const ushort_t* __restrict__ Hbf,
    float* __restrict__ Out)
{
    __shared__ alignas(16) ushort_t As[128 * 64];
    __shared__ alignas(16) ushort_t Bs[128 * 64];

    const int tid  = threadIdx.x;
    const int lane = tid & 63;
    const int wave = tid >> 6;
    const int wm   = wave & 1;
    const int wn   = wave >> 1;
    const int lrow = lane & 15;
    const int kgrp = lane >> 4;

    const int id  = blockIdx.x;
    const int xcd = id & 7;
    const int s   = id >> 3;
    const int mBase = (xcd + 8 * (s / NB2)) * 128;
    const int nBase = (s % NB2) * 128;

    f32x4 acc[4][4] = {};
    const ushort_t* Ablk = A  + (size_t)mBase * DH;
    const ushort_t* Bblk = Bt + (size_t)nBase * DIN;

    for (int k0 = 0; k0 < DIN; k0 += 64) {
        #pragma unroll
        for (int i = 0; i < 4; i++) {
            int idx = i * 256 + tid;
            int r   = idx >> 3;
            int cc  = ((idx & 7) ^ (r & 7)) * 8;
            load_lds16(Ablk + (size_t)r * DH  + k0 + cc, &As[idx * 8]);
            load_lds16(Bblk + (size_t)r * DIN + k0 + cc, &Bs[idx * 8]);
        }
        __syncthreads();
        #pragma unroll
        for (int kk = 0; kk < 64; kk += 32) {
            const int c0 = (kk >> 3) + kgrp;
            bf16x8 af[4], bfr[4];
            #pragma unroll
            for (int mt = 0; mt < 4; mt++) {
                int r = wm * 64 + mt * 16 + lrow;
                af[mt] = *(const bf16x8*)&As[r * 64 + (c0 ^ (r & 7)) * 8];
            }
            #pragma unroll
            for (int nt = 0; nt < 4; nt++) {
                int r = wn * 64 + nt * 16 + lrow;
                bfr[nt] = *(const bf16x8*)&Bs[r * 64 + (c0 ^ (r & 7)) * 8];
            }
            #pragma unroll
            for (int mt = 0; mt < 4; mt++)
                #pragma unroll
                for (int nt = 0; nt < 4; nt++)
                    acc[mt][nt] = __builtin_amdgcn_mfma_f32_16x16x32_bf16(
                        af[mt], bfr[nt], acc[mt][nt], 0, 0, 0);
        }
        __syncthreads();
    }

    // Stage H tile (128 rows x 128 cols bf16 = 32 KiB) into As/Bs region.
    ushort_t* Hs = As;   // As(16K)+Bs(16K) are contiguous -> 32 KiB
    #pragma unroll
    for (int it = 0; it < 8; it++) {
        int cid = it * 256 + tid;           // 0..2047 chunks of 16B
        int rr  = cid >> 4;                 // row 0..127
        int c   = cid & 15;                 // chunk 0..15
        int p   = c ^ (rr & 7);             // swizzled slot
        u16x8 v = *(const u16x8*)&Hbf[(size_t)(mBase + rr) * DH + nBase + c * 8];
        *(u16x8*)&Hs[rr * 128 + p * 8] = v;
    }
    __syncthreads();

    // Epilogue: per-element h from LDS, direct fp32 stores.
    const int row0  = mBase + wm * 64;
    const int col0  = nBase + wn * 64;
    const int rquad = (lane >> 4) * 4;

    #pragma unroll
    for (int nt = 0; nt < 4; nt++) {
        int colrel = wn * 64 + nt * 16 + lrow;
        int col    = nBase + colrel;
        float bv   = bg[col];
        int ck = colrel >> 3, c7 = colrel & 7;
        #pragma unroll
        for (int mt = 0; mt < 4; mt++) {
            int rowrel0 = wm * 64 + mt * 16 + rquad;
            #pragma unroll
            for (int r = 0; r < 4; r++) {
                int rr = rowrel0 + r;
                float h = bf2f(Hs[rr * 128 + ((ck ^ (rr & 7)) * 8) + c7]);
                float g = sigmoidf_(acc[mt][nt][r] + bv);
                Out[(size_t)(row0 + mt * 16 + rquad + r) * DH + col] = g * h;
            }
        }
    }
}

// ---------------------------------------------------------------------------
// Scan pass 1: per-chunk aggregates, 4 channels/thread (u16x4 = 8B loads).
__global__ __launch_bounds__(256) void scan_chunk_agg(
    const ushort_t* __restrict__ Zarr, const ushort_t* __restrict__ Harr,
    float* __restrict__ Agg, float* __restrict__ Bagg)
{
    const int c4    = threadIdx.x * 4;
    const int chunk = blockIdx.x;
    const int b     = blockIdx.y;
    const size_t s0 = ((size_t)b * SS + (size_t)chunk * CL) * DH + c4;
    const ushort_t* Zp = Zarr + s0;
    const ushort_t* Hp = Harr + s0;

    float A0 = 1.0f, A1 = 1.0f, A2 = 1.0f, A3 = 1.0f;
    float B0 = 0.0f, B1 = 0.0f, B2 = 0.0f, B3 = 0.0f;
    #pragma unroll 8
    for (int t = 0; t < CL; t++) {
        u16x4 zv = *(const u16x4*)(Zp + (size_t)t * DH);
        u16x4 hv = *(const u16x4*)(Hp + (size_t)t * DH);
        float z0 = bf2f(zv.x), z1 = bf2f(zv.y), z2 = bf2f(zv.z), z3 = bf2f(zv.w);
        float h0 = bf2f(hv.x), h1 = bf2f(hv.y), h2 = bf2f(hv.z), h3 = bf2f(hv.w);
        A0 *= 1.0f - z0;  B0 = (1.0f - z0) * B0 + z0 * h0;
        A1 *= 1.0f - z1;  B1 = (1.0f - z1) * B1 + z1 * h1;
        A2 *= 1.0f - z2;  B2 = (1.0f - z2) * B2 + z2 * h2;
        A3 *= 1.0f - z3;  B3 = (1.0f - z3) * B3 + z3 * h3;
    }
    const size_t idx = ((size_t)(b * NC + chunk)) * DH + c4;
    *(float4*)(Agg  + idx) = make_float4(A0, A1, A2, A3);
    *(float4*)(Bagg + idx) = make_float4(B0, B1, B2, B3);
}

// Scan pass 2 (carry fused in): each block derives its chunk-initial h by a
// local prefix over Agg/Bagg[0..chunk) (L2/L3-hot, <=63 FMAs), then applies
// the recurrence and writes h (bf16) in place over Harr.
__global__ __launch_bounds__(256) void scan_apply(
    const ushort_t* __restrict__ Zarr, ushort_t* Harr,
    const float* __restrict__ Agg, const float* __restrict__ Bagg)
{
    const int c4    = threadIdx.x * 4;
    const int chunk = blockIdx.x;
    const int b     = blockIdx.y;

    float h0 = 0.0f, h1 = 0.0f, h2 = 0.0f, h3 = 0.0f;
    for (int jj = 0; jj < chunk; jj++) {
        const size_t idx = ((size_t)(b * NC + jj)) * DH + c4;
        float4 Av = *(const float4*)(Agg  + idx);
        float4 Bv = *(const float4*)(Bagg + idx);
        h0 = Av.x * h0 + Bv.x;
        h1 = Av.y * h1 + Bv.y;
        h2 = Av.z * h2 + Bv.z;
        h3 = Av.w * h3 + Bv.w;
    }

    const size_t s0 = ((size_t)b * SS + (size_t)chunk * CL) * DH + c4;
    const ushort_t* Zp = Zarr + s0;
    ushort_t*       Hp = Harr + s0;
    #pragma unroll 8
    for (int t = 0; t < CL; t++) {
        u16x4 zv = *(const u16x4*)(Zp + (size_t)t * DH);
        u16x4 hv = *(const u16x4*)(Hp + (size_t)t * DH);
        float z0 = bf2f(zv.x), z1 = bf2f(zv.y), z2 = bf2f(zv.z), z3 = bf2f(zv.w);
        float t0 = bf2f(hv.x), t1 = bf2f(hv.y), t2 = bf2f(hv.z), t3 = bf2f(hv.w);
        h0 = (1.0f - z0) * h0 + z0 * t0;
        h1 = (1.0f - z1) * h1 + z1 * t1;
        h2 = (1.0f - z2) * h2 + z2 * t2;
        h3 = (1.0f - z3) * h3 + z3 * t3;
        u16x4 o;
        o.x = f2bf(h0); o.y = f2bf(h1); o.z = f2bf(h2); o.w = f2bf(h3);
        *(u16x4*)(Hp + (size_t)t * DH) = o;
    }
}

// ---------------------------------------------------------------------------
extern "C" void kernel_launch(void* const* d_in, const int* in_sizes, int n_in,
                              void* d_out, int out_size, void* d_ws, size_t ws_size,
                              hipStream_t stream)
{
    const float* x   = (const float*)d_in[0];
    const float* Wzf = (const float*)d_in[1];
    const float* bzf = (const float*)d_in[2];
    const float* Whf = (const float*)d_in[3];
    const float* bhf = (const float*)d_in[4];
    const float* Wzs = (const float*)d_in[5];
    const float* bzs = (const float*)d_in[6];
    const float* Whs = (const float*)d_in[7];
    const float* bhs = (const float*)d_in[8];
    const float* Wg  = (const float*)d_in[9];
    const float* bg  = (const float*)d_in[10];

    const size_t NEED = (size_t)42 << 20;
    if (ws_size < NEED) {
        zero_out_kernel<<<(MM * DH + 255) / 256, 256, 0, stream>>>((float*)d_out, MM * DH);
        return;
    }

    char* ws = (char*)d_ws;
    ushort_t* WcatT = (ushort_t*)(ws);                                    // 0..4 MiB
    ushort_t* WgT   = (ushort_t*)(ws + ((size_t)4 << 20));                // 4..6 MiB
    float*    bcat  = (float*)   (ws + ((size_t)6 << 20));                // 8 KiB
    float*    Agg   = (float*)   (ws + ((size_t)6 << 20) + (64 << 10));   // 1 MiB
    float*    Bagg  = (float*)   (ws + ((size_t)7 << 20) + (64 << 10));   // 1 MiB
    ushort_t* Harr  = (ushort_t*)(ws + ((size_t)10 << 20));               // 10..42 MiB

    ushort_t* Xb   = (ushort_t*)d_out;              // [0..32 MiB): x in bf16
    ushort_t* Zarr = Xb + (size_t)MM * DH;          // [32..64 MiB): post-sigmoid z

    dim3 blk(256);

    prep_kernel<<<PREP_NBLK, blk, 0, stream>>>(
        x, Wzf, Wzs, Whf, Whs, Wg, bzf, bzs, bhf, bhs, WcatT, WgT, Xb, bcat);

    gemm1_mfma<<<(MM / 128) * NB1, blk, 0, stream>>>(Xb, WcatT, bcat, Zarr, Harr);

    scan_chunk_agg<<<dim3(NC, BB), blk, 0, stream>>>(Zarr, Harr, Agg, Bagg);
    scan_apply<<<dim3(NC, BB), blk, 0, stream>>>(Zarr, Harr, Agg, Bagg);

    gemm2_mfma<<<(MM / 128) * NB2, blk, 0, stream>>>(Harr, WgT, bg, Harr, (float*)d_out);
}